// Round 16
// baseline (13475.371 us; speedup 1.0000x reference)
//
#include <hip/hip_runtime.h>
#include <math.h>

#define EMB    1024
#define HID    1024
#define BATCH    64
#define SEQ     512

#define NBG     16   // batch groups
#define BTILE    4   // batches per group
#define NJT     16   // j-tile WGs per batch group
#define JTILE   64   // j per tile

#define SLOT   65536 // floats per exchange slot; 2 slots in d_ws
#define STEPSZ 65536 // floats per timestep in out

typedef float f32x4 __attribute__((ext_vector_type(4)));
typedef float f32x2 __attribute__((ext_vector_type(2)));

// ---------------------------------------------------------------------------
__device__ __forceinline__ float red16(float x) {
    int xi, yi;
    xi = __builtin_bit_cast(int, x);
    yi = __builtin_amdgcn_update_dpp(0, xi, 0xB1, 0xF, 0xF, true);  // quad_perm xor1
    x += __builtin_bit_cast(float, yi);
    xi = __builtin_bit_cast(int, x);
    yi = __builtin_amdgcn_update_dpp(0, xi, 0x4E, 0xF, 0xF, true);  // quad_perm xor2
    x += __builtin_bit_cast(float, yi);
    xi = __builtin_bit_cast(int, x);
    yi = __builtin_amdgcn_update_dpp(0, xi, 0x124, 0xF, 0xF, true); // row_ror:4
    x += __builtin_bit_cast(float, yi);
    xi = __builtin_bit_cast(int, x);
    yi = __builtin_amdgcn_update_dpp(0, xi, 0x128, 0xF, 0xF, true); // row_ror:8
    x += __builtin_bit_cast(float, yi);
    return x;
}

// SYNC coherent loads (waitcnt inside — round-8 lesson).
// sc1: serviced at the LLC (device coherence point). sc0: L1-bypass, L2.
__device__ __forceinline__ f32x4 llc_load4_sync(const float* p) {
    f32x4 v;
    asm volatile("global_load_dwordx4 %0, %1, off sc1\n\t"
                 "s_waitcnt vmcnt(0)"
                 : "=&v"(v) : "v"(p) : "memory");
    return v;
}
__device__ __forceinline__ f32x4 l2_load4_sync(const float* p) {
    f32x4 v;
    asm volatile("global_load_dwordx4 %0, %1, off sc0\n\t"
                 "s_waitcnt vmcnt(0)"
                 : "=&v"(v) : "v"(p) : "memory");
    return v;
}
__device__ __forceinline__ void llc_load4x2_sync(const float* p0, const float* p1,
                                                 f32x4& a, f32x4& b) {
    asm volatile("global_load_dwordx4 %0, %2, off sc1\n\t"
                 "global_load_dwordx4 %1, %3, off sc1\n\t"
                 "s_waitcnt vmcnt(0)"
                 : "=&v"(a), "=&v"(b) : "v"(p0), "v"(p1) : "memory");
}
__device__ __forceinline__ void l2_load4x2_sync(const float* p0, const float* p1,
                                                f32x4& a, f32x4& b) {
    asm volatile("global_load_dwordx4 %0, %2, off sc0\n\t"
                 "global_load_dwordx4 %1, %3, off sc0\n\t"
                 "s_waitcnt vmcnt(0)"
                 : "=&v"(a), "=&v"(b) : "v"(p0), "v"(p1) : "memory");
}
// dual publish: plain store (L1-WT -> producer-XCD L2, fast path for
// same-XCD readers) + sc1 store (LLC, the always-correct path).
__device__ __forceinline__ void publish(float* p, float v) {
    asm volatile("global_store_dword %0, %1, off\n\t"
                 "global_store_dword %0, %1, off sc1"
                 :: "v"(p), "v"(v) : "memory");
}
__device__ __forceinline__ bool inrange4(f32x4 v, float lo, float hi) {
    return v.x >= lo && v.x <= hi && v.y >= lo && v.y <= hi &&
           v.z >= lo && v.z <= hi && v.w >= lo && v.w <= hi;
}

// ---------------------------------------------------------------------------
// FUSED kernel (r15 structure) + XCD-local h exchange.
//  - 1D grid remap puts all 16 WGs of a bg on one XCD (if HW round-robins
//    linear id % 8, m09). Correctness never assumes it: each WG registers
//    its TRUE XCD (s_getreg XCC_ID) in xcdtab; consumers use the fast L2
//    path only when the producer's registered XCD equals their own, with a
//    bounded-retry fallback to the sc1 path.
//  - Soundness of period-4 tags with dual copies: each publish is followed
//    by a vmcnt(0) (inside the next poll) before the next publish, so both
//    copies always hold h(x-1) or h(x-3) at consume; distance-2 tags block.
// ---------------------------------------------------------------------------
__global__ __launch_bounds__(512, 2) void rnn_fused(
    const float* __restrict__ embeds,  // (64,512,1024): row b*512+s
    const float* __restrict__ W_ih,    // HID x EMB
    const float* __restrict__ Whh,     // HID x HID
    const float* __restrict__ b_ih,
    const float* __restrict__ b_hh,
    float* __restrict__ out,           // (S,B,HID); xp then h in place
    float* __restrict__ exch,          // 2*SLOT floats, 0x7F-poisoned
    int*   __restrict__ xcdtab)        // NBG*NJT ints, zeroed
{
    const int tid  = threadIdx.x;
    const int wave = tid >> 6;
    const int lane = tid & 63;
    const int c    = lane & 15;

    // XCD-clustering remap: L%8 = (assumed) XCD; 32 WGs per XCD = 2 bgs.
    const int L   = blockIdx.x;
    const int kk_ = L >> 3;
    const int bg  = ((L & 7) << 1) | (kk_ >> 4);
    const int jt  = kk_ & 15;

    const int jbase = jt * JTILE + wave * 8 + ((lane >> 4) & 3) * 2;
    const int k0    = c * 64;

    // register true XCD identity early (poll happens after the prologue)
    int myxcc;
    asm volatile("s_getreg_b32 %0, hwreg(HW_REG_XCC_ID)" : "=s"(myxcc));
    myxcc &= 7;
    if (tid == 0) {
        __hip_atomic_store(&xcdtab[bg * NJT + jt], myxcc + 1,
                           __ATOMIC_RELAXED, __HIP_MEMORY_SCOPE_AGENT);
    }

    // --- W_hh slice -> registers, pinned ---
    f32x4 wr0[16], wr1[16];
    #pragma unroll
    for (int kq = 0; kq < 16; ++kq) {
        wr0[kq] = *(const f32x4*)&Whh[(size_t)jbase * HID + k0 + kq * 4];
        wr1[kq] = *(const f32x4*)&Whh[(size_t)(jbase + 1) * HID + k0 + kq * 4];
    }
    #pragma unroll
    for (int kq = 0; kq < 16; ++kq) {
        asm volatile("" : "+v"(wr0[kq]));
        asm volatile("" : "+v"(wr1[kq]));
    }

    // LDS: h double-buffer + xp A/W double-buffers
    __shared__ float hsf[2 * 4352];
    __shared__ float Axs[2][64][68];
    __shared__ float Wxs[2][64][68];

    // h staging: thread handles float4 idx tid and tid+512. NB r1==r0.
    const int b0i = tid >> 8,  r0 = tid & 255;
    const int b1i = b0i + 2;
    const int exoff0 = (bg * BTILE + b0i) * HID + r0 * 4;
    const int exoff1 = (bg * BTILE + b1i) * HID + r0 * 4;
    const int ldo0 = b0i * 1088 + (r0 >> 4) * 68 + (r0 & 15) * 4;
    const int ldo1 = b1i * 1088 + (r0 >> 4) * 68 + (r0 & 15) * 4;
    const int prodjt = r0 >> 4;    // producer jt of BOTH chunks

    // output ownership
    const int jout  = jbase + (c & 1);
    const int mybat = c >> 1;
    const int orow  = (bg * BTILE + mybat) * HID + jout;

    // xp-GEMM compute mapping
    const int gty = tid >> 5;
    const int gtx = tid & 31;
    const int jx0 = jt * 64 + gtx * 2;
    const float bias0 = b_ih[jx0] + b_hh[jx0];
    const float bias1 = b_ih[jx0 + 1] + b_hh[jx0 + 1];

    // xp staging mapping (conflict-free, r15)
    const bool isA  = (tid < 256);
    const int  st   = tid & 255;
    const int  srow = st >> 2;
    const int  kofs = (st & 3) * 4;

    f32x4 xaccA = {0.f,0.f,0.f,0.f};
    f32x4 xaccB = {0.f,0.f,0.f,0.f};

    auto xp_issue = [&](int sb, int kc, f32x4 v[4]) {
        const float* gp;
        if (isA) {
            gp = &embeds[((size_t)((bg*4 + (srow & 3)) * 512 + sb + (srow >> 2)) << 10)
                         + kc + kofs];
        } else {
            gp = &W_ih[((size_t)(jt*64 + srow) << 10) + kc + kofs];
        }
        #pragma unroll
        for (int s = 0; s < 4; ++s) v[s] = *(const f32x4*)(gp + s * 16);
    };
    auto xp_write = [&](int buf, const f32x4 v[4]) {
        float (*Arr)[68] = isA ? Axs[buf] : Wxs[buf];
        #pragma unroll
        for (int s = 0; s < 4; ++s) {
            Arr[s*16 + kofs + 0][srow] = v[s].x;
            Arr[s*16 + kofs + 1][srow] = v[s].y;
            Arr[s*16 + kofs + 2][srow] = v[s].z;
            Arr[s*16 + kofs + 3][srow] = v[s].w;
        }
    };
    auto xp_compute = [&](int buf) {
        #pragma unroll
        for (int kk = 0; kk < 64; ++kk) {
            f32x4 a4 = *(const f32x4*)&Axs[buf][kk][gty * 4];
            f32x2 w2 = *(const f32x2*)&Wxs[buf][kk][gtx * 2];
            xaccA += a4 * w2.x;
            xaccB += a4 * w2.y;
        }
    };
    auto xp_store = [&](int sbase) {
        float* o = &out[((size_t)((sbase + gty) * 64 + bg * 4) << 10) + jx0];
        *(f32x2*)(o +    0) = f32x2{xaccA.x + bias0, xaccB.x + bias1};
        *(f32x2*)(o + 1024) = f32x2{xaccA.y + bias0, xaccB.y + bias1};
        *(f32x2*)(o + 2048) = f32x2{xaccA.z + bias0, xaccB.z + bias1};
        *(f32x2*)(o + 3072) = f32x2{xaccA.w + bias0, xaccB.w + bias1};
        xaccA = f32x4{0.f,0.f,0.f,0.f};
        xaccB = f32x4{0.f,0.f,0.f,0.f};
    };

    // --- prologue: xp for s in [0,32) ---
    for (int q = 0; q < 32; ++q) {
        const int sb = (q >> 4) << 4;
        const int kc = (q & 15) << 6;
        f32x4 v[4];
        xp_issue(sb, kc, v);
        xp_write(q & 1, v);
        __syncthreads();
        xp_compute(q & 1);
        if ((q & 15) == 15) xp_store(sb);
    }
    __syncthreads();

    // --- resolve producer XCDs (table is complete ~instantly vs prologue) ---
    int tabv;
    {
        const int* tp = xcdtab + bg * NJT + (lane & 15);
        for (;;) {
            asm volatile("global_load_dword %0, %1, off sc1\n\t"
                         "s_waitcnt vmcnt(0)"
                         : "=&v"(tabv) : "v"(tp) : "memory");
            if (__all(tabv != 0)) break;
            __builtin_amdgcn_s_sleep(1);
        }
    }
    const bool fastP = (__shfl(tabv, prodjt) == myxcc + 1);

    // --- t = 0: h0 = tanh(xp0); dual-publish tag 0 into slot 0 ---
    if (c < 8) {
        float h0 = tanhf(out[orow]);
        out[orow] = h0;
        publish(&exch[orow], h0);
    }

    // --- t = 1 .. SEQ-1 ---
    for (int t = 1; t < SEQ; ++t) {
        float* cur = out + (size_t)t * STEPSZ;

        float xp = 0.f;
        if (c < 8) xp = cur[orow];

        // issue xp staging loads for quantum q = t-1 (hidden under the poll)
        const bool doxp = (t <= 480);
        const int  q    = t - 1;
        const int  xbuf = q & 1;
        const int  sb   = 32 + (q & ~15);
        const int  kc   = (q & 15) << 6;
        f32x4 vstage[4];
        if (doxp) {
            xp_issue(sb, kc, vstage);
            __builtin_amdgcn_sched_barrier(0);
        }

        // poll + fetch h(t-1): fast L2 path when producer is same-XCD,
        // sc1 LLC path otherwise; bounded fast retries then sc1 fallback.
        const float off = 4.0f * (float)((t - 1) & 3);
        const float lo  = off - 1.0f, hi = off + 1.0f;
        const float* eb = exch + ((t - 1) & 1) * SLOT;
        const float* e0 = eb + exoff0;
        const float* e1 = eb + exoff1;
        f32x4 v0, v1;
        if (fastP) l2_load4x2_sync(e0, e1, v0, v1);
        else       llc_load4x2_sync(e0, e1, v0, v1);
        bool ok0 = inrange4(v0, lo, hi);
        bool ok1 = inrange4(v1, lo, hi);
        int tries = 0;
        while (!__all(ok0 && ok1)) {
            __builtin_amdgcn_s_sleep(1);
            const bool uf = fastP && (tries++ < 64);
            if (!ok0) {
                v0 = uf ? l2_load4_sync(e0) : llc_load4_sync(e0);
                ok0 = inrange4(v0, lo, hi);
            }
            if (!ok1) {
                v1 = uf ? l2_load4_sync(e1) : llc_load4_sync(e1);
                ok1 = inrange4(v1, lo, hi);
            }
        }
        v0 -= off;
        v1 -= off;

        // stage h + stage xp, one barrier
        const int bufb = (t & 1) * 4352;
        *(f32x4*)&hsf[bufb + ldo0] = v0;
        *(f32x4*)&hsf[bufb + ldo1] = v1;
        if (doxp) xp_write(xbuf, vstage);
        __syncthreads();

        // h compute
        float acc[4][2];
        #pragma unroll
        for (int b = 0; b < 4; ++b) {
            const f32x4* hb = (const f32x4*)&hsf[bufb + b * 1088 + c * 68];
            f32x4 s0 = {0.f,0.f,0.f,0.f}, s1 = {0.f,0.f,0.f,0.f};
            #pragma unroll
            for (int kq = 0; kq < 16; ++kq) {
                f32x4 h4 = hb[kq];
                s0 += h4 * wr0[kq];
                s1 += h4 * wr1[kq];
            }
            acc[b][0] = (s0.x + s0.y) + (s0.z + s0.w);
            acc[b][1] = (s1.x + s1.y) + (s1.z + s1.w);
        }
        #pragma unroll
        for (int b = 0; b < 4; ++b) {
            acc[b][0] = red16(acc[b][0]);
            acc[b][1] = red16(acc[b][1]);
        }
        float vb0 = (c & 1) ? acc[0][1] : acc[0][0];
        float vb1 = (c & 1) ? acc[1][1] : acc[1][0];
        float vb2 = (c & 1) ? acc[2][1] : acc[2][0];
        float vb3 = (c & 1) ? acc[3][1] : acc[3][0];
        float vlo = (c & 2) ? vb1 : vb0;
        float vhi = (c & 2) ? vb3 : vb2;
        float v   = (c & 4) ? vhi : vlo;
        if (c < 8) {
            float hv = tanhf(xp + v);
            cur[orow] = hv;
            publish(&exch[(t & 1) * SLOT + orow], hv + 4.0f * (float)(t & 3));
        }

        // xp quantum compute (overlaps the h-exchange turnaround)
        if (doxp) {
            xp_compute(xbuf);
            if ((t & 15) == 0) xp_store(sb);
        }
    }
}

// ---------------------------------------------------------------------------
extern "C" void kernel_launch(void* const* d_in, const int* in_sizes, int n_in,
                              void* d_out, int out_size, void* d_ws, size_t ws_size,
                              hipStream_t stream) {
    const float* embeds = (const float*)d_in[0];
    const float* W_ih   = (const float*)d_in[1];
    const float* W_hh   = (const float*)d_in[2];
    const float* b_ih   = (const float*)d_in[3];
    const float* b_hh   = (const float*)d_in[4];
    float* out = (float*)d_out;

    (void)in_sizes; (void)n_in; (void)out_size; (void)ws_size;

    float* exch   = (float*)d_ws;
    int*   xcdtab = (int*)((char*)d_ws + (size_t)2 * SLOT * sizeof(float));

    // re-armed every replay (captured in the graph)
    hipMemsetAsync(d_ws, 0x7F, (size_t)2 * SLOT * sizeof(float), stream);
    hipMemsetAsync(xcdtab, 0, NBG * NJT * sizeof(int), stream);

    // single fused dispatch, 1D grid for the XCD-clustering remap
    rnn_fused<<<256, 512, 0, stream>>>(embeds, W_ih, W_hh, b_ih, b_hh,
                                       out, exch, xcdtab);
}

// Round 17
// 2769.012 us; speedup vs baseline: 4.8665x; 4.8665x over previous
//
#include <hip/hip_runtime.h>
#include <math.h>

#define EMB    1024
#define HID    1024
#define BATCH    64
#define SEQ     512

#define NBG     16   // batch groups
#define BTILE    4   // batches per group
#define NJT     16   // j-tile WGs per batch group
#define JTILE   64   // j per tile

#define SLOT   65536 // floats per exchange slot; 2 slots in d_ws
#define STEPSZ 65536 // floats per timestep in out

typedef float f32x4 __attribute__((ext_vector_type(4)));
typedef float f32x2 __attribute__((ext_vector_type(2)));

// ---------------------------------------------------------------------------
__device__ __forceinline__ float red16(float x) {
    int xi, yi;
    xi = __builtin_bit_cast(int, x);
    yi = __builtin_amdgcn_update_dpp(0, xi, 0xB1, 0xF, 0xF, true);  // quad_perm xor1
    x += __builtin_bit_cast(float, yi);
    xi = __builtin_bit_cast(int, x);
    yi = __builtin_amdgcn_update_dpp(0, xi, 0x4E, 0xF, 0xF, true);  // quad_perm xor2
    x += __builtin_bit_cast(float, yi);
    xi = __builtin_bit_cast(int, x);
    yi = __builtin_amdgcn_update_dpp(0, xi, 0x124, 0xF, 0xF, true); // row_ror:4
    x += __builtin_bit_cast(float, yi);
    xi = __builtin_bit_cast(int, x);
    yi = __builtin_amdgcn_update_dpp(0, xi, 0x128, 0xF, 0xF, true); // row_ror:8
    x += __builtin_bit_cast(float, yi);
    return x;
}

// SYNC 16B coherent loads from the LLC (waitcnt inside — round-8 lesson).
__device__ __forceinline__ f32x4 llc_load4_sync(const float* p) {
    f32x4 v;
    asm volatile("global_load_dwordx4 %0, %1, off sc1\n\t"
                 "s_waitcnt vmcnt(0)"
                 : "=&v"(v) : "v"(p) : "memory");
    return v;
}
__device__ __forceinline__ void llc_load4x2_sync(const float* p0, const float* p1,
                                                 f32x4& a, f32x4& b) {
    asm volatile("global_load_dwordx4 %0, %2, off sc1\n\t"
                 "global_load_dwordx4 %1, %3, off sc1\n\t"
                 "s_waitcnt vmcnt(0)"
                 : "=&v"(a), "=&v"(b) : "v"(p0), "v"(p1) : "memory");
}
// single 16B sc1 publish: the whole exchange chunk appears atomically —
// consumers can never observe a partially-written chunk.
__device__ __forceinline__ void llc_store4(float* p, f32x4 v) {
    asm volatile("global_store_dwordx4 %0, %1, off sc1"
                 :: "v"(p), "v"(v) : "memory");
}
__device__ __forceinline__ bool inrange4(f32x4 v, float lo, float hi) {
    return v.x >= lo && v.x <= hi && v.y >= lo && v.y <= hi &&
           v.z >= lo && v.z <= hi && v.w >= lo && v.w <= hi;
}

// ---------------------------------------------------------------------------
// FUSED kernel (r15 structure) with 16B-atomic publishes.
//  - h exchange: value-tagged sc1 (tag 4*(t%4), slot t%2, 0x7F sentinel).
//  - publish: ONE lane per (batch, j-quad) writes one dwordx4 (after a
//    shfl_xor(16) pairing of adjacent jp-groups) -> no partial chunks,
//    4x fewer publish transactions, vectorized out writes.
//  - xp: per-WG own-slice GEMM quanta hidden under the poll (r14/r15).
// ---------------------------------------------------------------------------
__global__ __launch_bounds__(512, 2) void rnn_fused(
    const float* __restrict__ embeds,  // (64,512,1024): row b*512+s
    const float* __restrict__ W_ih,    // HID x EMB
    const float* __restrict__ Whh,     // HID x HID
    const float* __restrict__ b_ih,
    const float* __restrict__ b_hh,
    float* __restrict__ out,           // (S,B,HID); xp then h in place
    float* __restrict__ exch)          // 2*SLOT floats, 0x7F-poisoned
{
    const int tid  = threadIdx.x;
    const int wave = tid >> 6;
    const int lane = tid & 63;
    const int c    = lane & 15;
    const int jp   = (lane >> 4) & 3;
    const int jt   = blockIdx.x;
    const int bg   = blockIdx.y;
    const int jbase = jt * JTILE + wave * 8 + jp * 2;
    const int k0    = c * 64;

    // --- W_hh slice -> registers, pinned ---
    f32x4 wr0[16], wr1[16];
    #pragma unroll
    for (int kq = 0; kq < 16; ++kq) {
        wr0[kq] = *(const f32x4*)&Whh[(size_t)jbase * HID + k0 + kq * 4];
        wr1[kq] = *(const f32x4*)&Whh[(size_t)(jbase + 1) * HID + k0 + kq * 4];
    }
    #pragma unroll
    for (int kq = 0; kq < 16; ++kq) {
        asm volatile("" : "+v"(wr0[kq]));
        asm volatile("" : "+v"(wr1[kq]));
    }

    // LDS: h double-buffer + xp A/W double-buffers
    __shared__ float hsf[2 * 4352];
    __shared__ float Axs[2][64][68];
    __shared__ float Wxs[2][64][68];

    // h staging: thread handles float4 idx tid and tid+512 (r9 mapping)
    const int b0i = tid >> 8,  r0 = tid & 255;
    const int b1i = b0i + 2;
    const int exoff0 = (bg * BTILE + b0i) * HID + r0 * 4;
    const int exoff1 = (bg * BTILE + b1i) * HID + r0 * 4;
    const int ldo0 = b0i * 1088 + (r0 >> 4) * 68 + (r0 & 15) * 4;
    const int ldo1 = b1i * 1088 + (r0 >> 4) * 68 + (r0 & 15) * 4;

    // writer role: one lane per (batch, j-quad): jp even, c<4 -> batch=c,
    // quad j0 = jt*64 + wave*8 + (jp>>1)*4 (own j0,j0+1; partner j0+2,j0+3)
    const bool wrt = ((jp & 1) == 0) && (c < 4);
    const int  wj0 = jt * 64 + wave * 8 + (jp >> 1) * 4;
    const int  wrow = (bg * BTILE + c) * HID + wj0;   // valid when wrt

    // xp-GEMM compute mapping (r15)
    const int gty = tid >> 5;
    const int gtx = tid & 31;
    const int jx0 = jt * 64 + gtx * 2;
    const float bias0 = b_ih[jx0] + b_hh[jx0];
    const float bias1 = b_ih[jx0 + 1] + b_hh[jx0 + 1];

    // xp staging mapping (conflict-free, r15)
    const bool isA  = (tid < 256);
    const int  st   = tid & 255;
    const int  srow = st >> 2;
    const int  kofs = (st & 3) * 4;

    f32x4 xaccA = {0.f,0.f,0.f,0.f};
    f32x4 xaccB = {0.f,0.f,0.f,0.f};

    auto xp_issue = [&](int sb, int kc, f32x4 v[4]) {
        const float* gp;
        if (isA) {
            gp = &embeds[((size_t)((bg*4 + (srow & 3)) * 512 + sb + (srow >> 2)) << 10)
                         + kc + kofs];
        } else {
            gp = &W_ih[((size_t)(jt*64 + srow) << 10) + kc + kofs];
        }
        #pragma unroll
        for (int s = 0; s < 4; ++s) v[s] = *(const f32x4*)(gp + s * 16);
    };
    auto xp_write = [&](int buf, const f32x4 v[4]) {
        float (*Arr)[68] = isA ? Axs[buf] : Wxs[buf];
        #pragma unroll
        for (int s = 0; s < 4; ++s) {
            Arr[s*16 + kofs + 0][srow] = v[s].x;
            Arr[s*16 + kofs + 1][srow] = v[s].y;
            Arr[s*16 + kofs + 2][srow] = v[s].z;
            Arr[s*16 + kofs + 3][srow] = v[s].w;
        }
    };
    auto xp_compute = [&](int buf) {
        #pragma unroll
        for (int kk = 0; kk < 64; ++kk) {
            f32x4 a4 = *(const f32x4*)&Axs[buf][kk][gty * 4];
            f32x2 w2 = *(const f32x2*)&Wxs[buf][kk][gtx * 2];
            xaccA += a4 * w2.x;
            xaccB += a4 * w2.y;
        }
    };
    auto xp_store = [&](int sbase) {
        float* o = &out[((size_t)((sbase + gty) * 64 + bg * 4) << 10) + jx0];
        *(f32x2*)(o +    0) = f32x2{xaccA.x + bias0, xaccB.x + bias1};
        *(f32x2*)(o + 1024) = f32x2{xaccA.y + bias0, xaccB.y + bias1};
        *(f32x2*)(o + 2048) = f32x2{xaccA.z + bias0, xaccB.z + bias1};
        *(f32x2*)(o + 3072) = f32x2{xaccA.w + bias0, xaccB.w + bias1};
        xaccA = f32x4{0.f,0.f,0.f,0.f};
        xaccB = f32x4{0.f,0.f,0.f,0.f};
    };

    // --- prologue: xp for s in [0,32) ---
    for (int q = 0; q < 32; ++q) {
        const int sb = (q >> 4) << 4;
        const int kc = (q & 15) << 6;
        f32x4 v[4];
        xp_issue(sb, kc, v);
        xp_write(q & 1, v);
        __syncthreads();
        xp_compute(q & 1);
        if ((q & 15) == 15) xp_store(sb);
    }
    __syncthreads();

    // --- t = 0: h0 = tanh(xp0) per quad; 16B publish (tag 0) ---
    if (wrt) {
        f32x4 xq = *(const f32x4*)&out[wrow];
        f32x4 h0 = {tanhf(xq.x), tanhf(xq.y), tanhf(xq.z), tanhf(xq.w)};
        *(f32x4*)&out[wrow] = h0;
        llc_store4(&exch[wrow], h0);
    }

    // --- t = 1 .. SEQ-1 ---
    for (int t = 1; t < SEQ; ++t) {
        float* cur = out + (size_t)t * STEPSZ;

        // xp quad for this step (self-written >=16 steps ago; plain load)
        f32x4 xq = {0.f,0.f,0.f,0.f};
        if (wrt) xq = *(const f32x4*)&cur[wrow];

        // issue xp staging loads for quantum q = t-1 (hidden under the poll)
        const bool doxp = (t <= 480);
        const int  q    = t - 1;
        const int  xbuf = q & 1;
        const int  sb   = 32 + (q & ~15);
        const int  kc   = (q & 15) << 6;
        f32x4 vstage[4];
        if (doxp) {
            xp_issue(sb, kc, vstage);
            __builtin_amdgcn_sched_barrier(0);
        }

        // poll + fetch h(t-1) — value-tagged; chunks are 16B-atomic now
        const float off = 4.0f * (float)((t - 1) & 3);
        const float lo  = off - 1.0f, hi = off + 1.0f;
        const float* eb = exch + ((t - 1) & 1) * SLOT;
        const float* e0 = eb + exoff0;
        const float* e1 = eb + exoff1;
        f32x4 v0, v1;
        llc_load4x2_sync(e0, e1, v0, v1);
        bool ok0 = inrange4(v0, lo, hi);
        bool ok1 = inrange4(v1, lo, hi);
        while (!__all(ok0 && ok1)) {
            __builtin_amdgcn_s_sleep(1);
            if (!ok0 && !ok1) {
                llc_load4x2_sync(e0, e1, v0, v1);
                ok0 = inrange4(v0, lo, hi);
                ok1 = inrange4(v1, lo, hi);
            } else if (!ok0) {
                v0 = llc_load4_sync(e0); ok0 = inrange4(v0, lo, hi);
            } else {
                v1 = llc_load4_sync(e1); ok1 = inrange4(v1, lo, hi);
            }
        }
        v0 -= off;
        v1 -= off;

        // stage h + stage xp, one barrier
        const int bufb = (t & 1) * 4352;
        *(f32x4*)&hsf[bufb + ldo0] = v0;
        *(f32x4*)&hsf[bufb + ldo1] = v1;
        if (doxp) xp_write(xbuf, vstage);
        __syncthreads();

        // h compute (all lanes; red16 leaves group-uniform sums)
        float acc[4][2];
        #pragma unroll
        for (int b = 0; b < 4; ++b) {
            const f32x4* hb = (const f32x4*)&hsf[bufb + b * 1088 + c * 68];
            f32x4 s0 = {0.f,0.f,0.f,0.f}, s1 = {0.f,0.f,0.f,0.f};
            #pragma unroll
            for (int kq = 0; kq < 16; ++kq) {
                f32x4 h4 = hb[kq];
                s0 += h4 * wr0[kq];
                s1 += h4 * wr1[kq];
            }
            acc[b][0] = (s0.x + s0.y) + (s0.z + s0.w);
            acc[b][1] = (s1.x + s1.y) + (s1.z + s1.w);
        }
        #pragma unroll
        for (int b = 0; b < 4; ++b) {
            acc[b][0] = red16(acc[b][0]);
            acc[b][1] = red16(acc[b][1]);
        }

        // pair jp-groups: lane^16 swaps with the adjacent group (j +/- 2)
        float pa0[4], pa1[4];
        #pragma unroll
        for (int b = 0; b < 4; ++b) {
            pa0[b] = __shfl_xor(acc[b][0], 16);
            pa1[b] = __shfl_xor(acc[b][1], 16);
        }

        // writer lane: batch=c, quad = (own j0,j0+1 | partner j0+2,j0+3)
        if (wrt) {
            f32x4 hv;
            hv.x = tanhf(xq.x + acc[c][0]);
            hv.y = tanhf(xq.y + acc[c][1]);
            hv.z = tanhf(xq.z + pa0[c]);
            hv.w = tanhf(xq.w + pa1[c]);
            *(f32x4*)&cur[wrow] = hv;                    // output (16B plain)
            llc_store4(&exch[(t & 1) * SLOT + wrow],
                       hv + 4.0f * (float)(t & 3));      // 16B atomic publish
        }

        // xp quantum compute (overlaps the h-exchange turnaround)
        if (doxp) {
            xp_compute(xbuf);
            if ((t & 15) == 0) xp_store(sb);
        }
    }
}

// ---------------------------------------------------------------------------
extern "C" void kernel_launch(void* const* d_in, const int* in_sizes, int n_in,
                              void* d_out, int out_size, void* d_ws, size_t ws_size,
                              hipStream_t stream) {
    const float* embeds = (const float*)d_in[0];
    const float* W_ih   = (const float*)d_in[1];
    const float* W_hh   = (const float*)d_in[2];
    const float* b_ih   = (const float*)d_in[3];
    const float* b_hh   = (const float*)d_in[4];
    float* out = (float*)d_out;

    (void)in_sizes; (void)n_in; (void)out_size; (void)ws_size;

    // poison exchange buffer (outside every tag range); graph-captured so
    // re-armed on every replay.
    hipMemsetAsync(d_ws, 0x7F, (size_t)2 * SLOT * sizeof(float), stream);

    // single fused dispatch (2D grid — r15 layout)
    dim3 gR(NJT, NBG);
    rnn_fused<<<gR, 512, 0, stream>>>(embeds, W_ih, W_hh, b_ih, b_hh,
                                      out, (float*)d_ws);
}

// Round 18
// 2346.039 us; speedup vs baseline: 5.7439x; 1.1803x over previous
//
#include <hip/hip_runtime.h>
#include <math.h>

#define EMB    1024
#define HID    1024
#define BATCH    64
#define SEQ     512

#define NBG     16   // batch groups
#define BTILE    4   // batches per group
#define NJT     16   // j-tile WGs per batch group
#define JTILE   64   // j per tile

#define SLOT   65536 // floats per exchange slot; 2 slots in d_ws
#define STEPSZ 65536 // floats per timestep in out

typedef float f32x4 __attribute__((ext_vector_type(4)));
typedef float f32x2 __attribute__((ext_vector_type(2)));

// ---------------------------------------------------------------------------
// 16-lane VALU DPP sum reduction (all 16 lanes end with the group sum).
// ---------------------------------------------------------------------------
__device__ __forceinline__ float red16(float x) {
    int xi, yi;
    xi = __builtin_bit_cast(int, x);
    yi = __builtin_amdgcn_update_dpp(0, xi, 0xB1, 0xF, 0xF, true);  // quad_perm xor1
    x += __builtin_bit_cast(float, yi);
    xi = __builtin_bit_cast(int, x);
    yi = __builtin_amdgcn_update_dpp(0, xi, 0x4E, 0xF, 0xF, true);  // quad_perm xor2
    x += __builtin_bit_cast(float, yi);
    xi = __builtin_bit_cast(int, x);
    yi = __builtin_amdgcn_update_dpp(0, xi, 0x124, 0xF, 0xF, true); // row_ror:4
    x += __builtin_bit_cast(float, yi);
    xi = __builtin_bit_cast(int, x);
    yi = __builtin_amdgcn_update_dpp(0, xi, 0x128, 0xF, 0xF, true); // row_ror:8
    x += __builtin_bit_cast(float, yi);
    return x;
}

// SYNC 16B coherent loads from the LLC (waitcnt inside — round-8 lesson).
__device__ __forceinline__ f32x4 llc_load4_sync(const float* p) {
    f32x4 v;
    asm volatile("global_load_dwordx4 %0, %1, off sc1\n\t"
                 "s_waitcnt vmcnt(0)"
                 : "=&v"(v) : "v"(p) : "memory");
    return v;
}
__device__ __forceinline__ void llc_load4x2_sync(const float* p0, const float* p1,
                                                 f32x4& a, f32x4& b) {
    asm volatile("global_load_dwordx4 %0, %2, off sc1\n\t"
                 "global_load_dwordx4 %1, %3, off sc1\n\t"
                 "s_waitcnt vmcnt(0)"
                 : "=&v"(a), "=&v"(b) : "v"(p0), "v"(p1) : "memory");
}
__device__ __forceinline__ bool inrange4(f32x4 v, float lo, float hi) {
    return v.x >= lo && v.x <= hi && v.y >= lo && v.y <= hi &&
           v.z >= lo && v.z <= hi && v.w >= lo && v.w <= hi;
}

// ---------------------------------------------------------------------------
// FUSED kernel (r14 structure), xp staging CONFLICT-FREE (r15 — best):
//  - h exchange: r9 value-tagged sc1 protocol — only cross-WG communication.
//  - xp: each WG computes its OWN slice; per-step 64m x 64n x 64k quantum;
//    s-block [32+16i,48+16i) computed during steps 16i+1..16i+16; s<32 in a
//    prologue. Same-WG produce/consume via plain cached memory.
//  - Staging mapping (the r0 xproj_gemm pattern, measured 0 conflicts):
//    tid<256 -> A, tid>=256 -> W; row srow=(tid&255)>>2, kofs=(tid&3)*4,
//    4 slabs of 16k. Write bank = ((tid&3)*16 + 4j + tid>>2) mod 32 ->
//    2-way aliasing only (free). 4 consecutive lanes read 64B of one row.
// ---------------------------------------------------------------------------
__global__ __launch_bounds__(512, 2) void rnn_fused(
    const float* __restrict__ embeds,  // (64,512,1024): row b*512+s
    const float* __restrict__ W_ih,    // HID x EMB
    const float* __restrict__ Whh,     // HID x HID
    const float* __restrict__ b_ih,
    const float* __restrict__ b_hh,
    float* __restrict__ out,           // (S,B,HID); xp then h in place
    float* __restrict__ exch)          // 2*SLOT floats, 0x7F-poisoned
{
    const int tid  = threadIdx.x;
    const int wave = tid >> 6;
    const int lane = tid & 63;
    const int c    = lane & 15;
    const int jt   = blockIdx.x;
    const int bg   = blockIdx.y;
    const int jbase = jt * JTILE + wave * 8 + ((lane >> 4) & 3) * 2;
    const int k0    = c * 64;

    // --- W_hh slice -> registers, pinned ---
    f32x4 wr0[16], wr1[16];
    #pragma unroll
    for (int kq = 0; kq < 16; ++kq) {
        wr0[kq] = *(const f32x4*)&Whh[(size_t)jbase * HID + k0 + kq * 4];
        wr1[kq] = *(const f32x4*)&Whh[(size_t)(jbase + 1) * HID + k0 + kq * 4];
    }
    #pragma unroll
    for (int kq = 0; kq < 16; ++kq) {
        asm volatile("" : "+v"(wr0[kq]));
        asm volatile("" : "+v"(wr1[kq]));
    }

    // LDS: h double-buffer + xp A/W double-buffers
    __shared__ float hsf[2 * 4352];
    __shared__ float Axs[2][64][68];   // [k][m], m = si*4+bloc
    __shared__ float Wxs[2][64][68];   // [k][n]

    // h staging (r9): thread handles float4 idx tid and tid+512
    const int b0i = tid >> 8,         r0 = tid & 255;
    const int b1i = (tid + 512) >> 8, r1 = (tid + 512) & 255;
    const int exoff0 = (bg * BTILE + b0i) * HID + r0 * 4;
    const int exoff1 = (bg * BTILE + b1i) * HID + r1 * 4;
    const int ldo0 = b0i * 1088 + (r0 >> 4) * 68 + (r0 & 15) * 4;
    const int ldo1 = b1i * 1088 + (r1 >> 4) * 68 + (r1 & 15) * 4;

    // output ownership: lanes c<8 own (batch = c>>1, j = jbase + (c&1))
    const int jout  = jbase + (c & 1);
    const int mybat = c >> 1;
    const int orow  = (bg * BTILE + mybat) * HID + jout;

    // xp-GEMM compute mapping: 512 thr = 16 gty x 32 gtx; micro 4m x 2n.
    const int gty = tid >> 5;
    const int gtx = tid & 31;
    const int jx0 = jt * 64 + gtx * 2;
    const float bias0 = b_ih[jx0] + b_hh[jx0];
    const float bias1 = b_ih[jx0 + 1] + b_hh[jx0 + 1];

    // xp staging mapping (conflict-free)
    const bool isA  = (tid < 256);
    const int  st   = tid & 255;
    const int  srow = st >> 2;         // 0..63 (m for A, n for W)
    const int  kofs = (st & 3) * 4;    // 0,4,8,12

    f32x4 xaccA = {0.f,0.f,0.f,0.f};   // ni=0
    f32x4 xaccB = {0.f,0.f,0.f,0.f};   // ni=1

    auto xp_issue = [&](int sb, int kc, f32x4 v[4]) {
        const float* gp;
        if (isA) {
            gp = &embeds[((size_t)((bg*4 + (srow & 3)) * 512 + sb + (srow >> 2)) << 10)
                         + kc + kofs];
        } else {
            gp = &W_ih[((size_t)(jt*64 + srow) << 10) + kc + kofs];
        }
        #pragma unroll
        for (int s = 0; s < 4; ++s) v[s] = *(const f32x4*)(gp + s * 16);
    };
    auto xp_write = [&](int buf, const f32x4 v[4]) {
        float (*Arr)[68] = isA ? Axs[buf] : Wxs[buf];
        #pragma unroll
        for (int s = 0; s < 4; ++s) {
            Arr[s*16 + kofs + 0][srow] = v[s].x;
            Arr[s*16 + kofs + 1][srow] = v[s].y;
            Arr[s*16 + kofs + 2][srow] = v[s].z;
            Arr[s*16 + kofs + 3][srow] = v[s].w;
        }
    };
    auto xp_compute = [&](int buf) {
        #pragma unroll
        for (int kk = 0; kk < 64; ++kk) {
            f32x4 a4 = *(const f32x4*)&Axs[buf][kk][gty * 4];
            f32x2 w2 = *(const f32x2*)&Wxs[buf][kk][gtx * 2];
            xaccA += a4 * w2.x;
            xaccB += a4 * w2.y;
        }
    };
    auto xp_store = [&](int sbase) {
        float* o = &out[((size_t)((sbase + gty) * 64 + bg * 4) << 10) + jx0];
        *(f32x2*)(o +    0) = f32x2{xaccA.x + bias0, xaccB.x + bias1};
        *(f32x2*)(o + 1024) = f32x2{xaccA.y + bias0, xaccB.y + bias1};
        *(f32x2*)(o + 2048) = f32x2{xaccA.z + bias0, xaccB.z + bias1};
        *(f32x2*)(o + 3072) = f32x2{xaccA.w + bias0, xaccB.w + bias1};
        xaccA = f32x4{0.f,0.f,0.f,0.f};
        xaccB = f32x4{0.f,0.f,0.f,0.f};
    };

    // --- prologue: xp for s in [0,32), 32 quanta ---
    for (int q = 0; q < 32; ++q) {
        const int sb = (q >> 4) << 4;
        const int kc = (q & 15) << 6;
        f32x4 v[4];
        xp_issue(sb, kc, v);
        xp_write(q & 1, v);
        __syncthreads();
        xp_compute(q & 1);
        if ((q & 15) == 15) xp_store(sb);
    }
    __syncthreads();

    // --- t = 0: h0 = tanh(xp0); publish tag 0 into slot 0 ---
    if (c < 8) {
        float h0 = tanhf(out[orow]);
        out[orow] = h0;
        __hip_atomic_store(&exch[orow], h0, __ATOMIC_RELAXED,
                           __HIP_MEMORY_SCOPE_AGENT);
    }

    // --- t = 1 .. SEQ-1 ---
    for (int t = 1; t < SEQ; ++t) {
        float* cur = out + (size_t)t * STEPSZ;

        // xp for this step (self-written >=16 steps ago; plain cached load)
        float xp = 0.f;
        if (c < 8) xp = cur[orow];

        // issue xp staging loads for quantum q = t-1 (hidden under the poll)
        const bool doxp = (t <= 480);
        const int  q    = t - 1;
        const int  xbuf = q & 1;
        const int  sb   = 32 + (q & ~15);
        const int  kc   = (q & 15) << 6;
        f32x4 vstage[4];
        if (doxp) {
            xp_issue(sb, kc, vstage);
            __builtin_amdgcn_sched_barrier(0);
        }

        // poll + fetch h(t-1) — r9 value-tagged protocol
        const float off = 4.0f * (float)((t - 1) & 3);
        const float lo  = off - 1.0f, hi = off + 1.0f;
        const float* eb = exch + ((t - 1) & 1) * SLOT;
        f32x4 v0, v1;
        llc_load4x2_sync(eb + exoff0, eb + exoff1, v0, v1);
        bool ok0 = inrange4(v0, lo, hi);
        bool ok1 = inrange4(v1, lo, hi);
        while (!__all(ok0 && ok1)) {
            __builtin_amdgcn_s_sleep(1);
            if (!ok0) { v0 = llc_load4_sync(eb + exoff0); ok0 = inrange4(v0, lo, hi); }
            if (!ok1) { v1 = llc_load4_sync(eb + exoff1); ok1 = inrange4(v1, lo, hi); }
        }
        v0 -= off;
        v1 -= off;

        // stage h + stage xp, one barrier
        const int bufb = (t & 1) * 4352;
        *(f32x4*)&hsf[bufb + ldo0] = v0;
        *(f32x4*)&hsf[bufb + ldo1] = v1;
        if (doxp) xp_write(xbuf, vstage);
        __syncthreads();

        // h compute (r9)
        float acc[4][2];
        #pragma unroll
        for (int b = 0; b < 4; ++b) {
            const f32x4* hb = (const f32x4*)&hsf[bufb + b * 1088 + c * 68];
            f32x4 s0 = {0.f,0.f,0.f,0.f}, s1 = {0.f,0.f,0.f,0.f};
            #pragma unroll
            for (int kq = 0; kq < 16; ++kq) {
                f32x4 h4 = hb[kq];
                s0 += h4 * wr0[kq];
                s1 += h4 * wr1[kq];
            }
            acc[b][0] = (s0.x + s0.y) + (s0.z + s0.w);
            acc[b][1] = (s1.x + s1.y) + (s1.z + s1.w);
        }
        #pragma unroll
        for (int b = 0; b < 4; ++b) {
            acc[b][0] = red16(acc[b][0]);
            acc[b][1] = red16(acc[b][1]);
        }
        float vb0 = (c & 1) ? acc[0][1] : acc[0][0];
        float vb1 = (c & 1) ? acc[1][1] : acc[1][0];
        float vb2 = (c & 1) ? acc[2][1] : acc[2][0];
        float vb3 = (c & 1) ? acc[3][1] : acc[3][0];
        float vlo = (c & 2) ? vb1 : vb0;
        float vhi = (c & 2) ? vb3 : vb2;
        float v   = (c & 4) ? vhi : vlo;
        if (c < 8) {
            float hv = tanhf(xp + v);
            cur[orow] = hv;
            __hip_atomic_store(&exch[(t & 1) * SLOT + orow],
                               hv + 4.0f * (float)(t & 3),
                               __ATOMIC_RELAXED, __HIP_MEMORY_SCOPE_AGENT);
        }

        // xp quantum compute (overlaps the h-exchange turnaround)
        if (doxp) {
            xp_compute(xbuf);
            if ((t & 15) == 0) xp_store(sb);   // q&15==15 -> block complete
        }
    }
}

// ---------------------------------------------------------------------------
extern "C" void kernel_launch(void* const* d_in, const int* in_sizes, int n_in,
                              void* d_out, int out_size, void* d_ws, size_t ws_size,
                              hipStream_t stream) {
    const float* embeds = (const float*)d_in[0];
    const float* W_ih   = (const float*)d_in[1];
    const float* W_hh   = (const float*)d_in[2];
    const float* b_ih   = (const float*)d_in[3];
    const float* b_hh   = (const float*)d_in[4];
    float* out = (float*)d_out;

    (void)in_sizes; (void)n_in; (void)out_size; (void)ws_size;

    // poison exchange buffer (outside every tag range); graph-captured so
    // re-armed on every replay.
    hipMemsetAsync(d_ws, 0x7F, (size_t)2 * SLOT * sizeof(float), stream);

    // single fused dispatch
    dim3 gR(NJT, NBG);
    rnn_fused<<<gR, 512, 0, stream>>>(embeds, W_ih, W_hh, b_ih, b_hh,
                                      out, (float*)d_ws);
}